// Round 9
// baseline (115.152 us; speedup 1.0000x reference)
//
#include <hip/hip_runtime.h>
#include <hip/hip_bf16.h>
#include <hip/hip_fp16.h>

#define N_PTS 131072
#define RES_A 128
#define RES_B 256

typedef __attribute__((ext_vector_type(8))) short short8;
typedef __attribute__((ext_vector_type(4))) short short4v;
typedef __attribute__((ext_vector_type(4))) float f32x4;
typedef __attribute__((ext_vector_type(4))) unsigned int u32x4;
typedef __attribute__((ext_vector_type(8))) _Float16 half8;

// f16 transposed grids: [axis][i][d*8+cc] -> 16B (8 halfs) per (i,d) slice.
__device__ __align__(16) short g_gta[3 * RES_A * 128];
__device__ __align__(16) short g_gtb[3 * RES_B * 128];
// f16 A-fragments: [scale][half][x(16)][k(32)]; k=g*8+j <-> C[x][y=2g+half][z=j]; x>=8 -> 0.
__device__ __align__(16) short g_cbf[2 * 1024];

__device__ __forceinline__ short hbits(float x) {
  __half h = __float2half(x);
  return *reinterpret_cast<short*>(&h);
}

// LDS-tiled transpose to f16 + core f16 fragment build. (Identical to R7.)
__global__ __launch_bounds__(256) void prep_kernel(
    const float* __restrict__ g0a, const float* __restrict__ g1a,
    const float* __restrict__ g2a, const float* __restrict__ corea,
    const float* __restrict__ g0b, const float* __restrict__ g1b,
    const float* __restrict__ g2b, const float* __restrict__ coreb) {
  __shared__ float tile[32][33];
  const int bid = blockIdx.x;
  if (bid < 144) {
    int r, axis, tl;
    const float* src;
    short* dst;
    if (bid < 48) {
      r = RES_A; axis = bid / 16; tl = bid % 16;
      src = axis == 0 ? g0a : (axis == 1 ? g1a : g2a);
      dst = g_gta + axis * (RES_A * 128);
    } else {
      const int u = bid - 48;
      r = RES_B; axis = u / 32; tl = u % 32;
      src = axis == 0 ? g0b : (axis == 1 ? g1b : g2b);
      dst = g_gtb + axis * (RES_B * 128);
    }
    const int it = tl >> 2, dct = tl & 3;
    const int i0 = it * 32, dc0 = dct * 32;
    const int tx = threadIdx.x & 31, ty = threadIdx.x >> 5;
#pragma unroll
    for (int k = 0; k < 4; ++k)
      tile[ty + k * 8][tx] = src[(dc0 + ty + k * 8) * r + i0 + tx];
    __syncthreads();
#pragma unroll
    for (int k = 0; k < 4; ++k)
      dst[(i0 + ty + k * 8) * 128 + dc0 + tx] = hbits(tile[tx][ty + k * 8]);
  } else {
    const int e = (bid - 144) * 256 + threadIdx.x;   // 0..2047
    const int scale = e >> 10, rem = e & 1023;
    const int half = rem >> 9, x = (rem >> 5) & 15, k = rem & 31;
    const int gg = k >> 3, j = k & 7;
    const float* C = scale ? coreb : corea;
    const int y = 2 * gg + half;
    g_cbf[e] = hbits(x < 8 ? C[x * 64 + y * 8 + j] : 0.0f);
  }
}

// One wave per (4 points, scale). Lane-parallel preamble: lane t<12 computes
// position math for (point t/3, axis t%3) -- its coord is pts[n0*3+t], one
// coalesced load, zero select chains. Staging offsets + weight splats are
// distributed via __shfl. Then (identical to the passing R7): 6 dwordx4
// gathers, LDS stage, __syncthreads, per point packed-f16 lerp + products,
// 2x mfma_f32_16x16x32_f16, dot + shfl reduce.
__global__ __launch_bounds__(256) void tucker_mfma(
    const float* __restrict__ pts, float* __restrict__ out) {
  __shared__ short lds[4][3072];       // 6 buffers x 1KB per wave
  const int t = threadIdx.x & 63;
  const int wv = __builtin_amdgcn_readfirstlane(threadIdx.x >> 6);
  const int scale = blockIdx.y;
  const int n0 = blockIdx.x * 16 + wv * 4;
  const int c = t & 15, g = t >> 4;

  const short* __restrict__ gt = scale ? g_gtb : g_gta;
  const short* __restrict__ cb = g_cbf + scale * 1024;
  const int r = scale ? RES_B : RES_A;
  const float half_rm1 = 0.5f * (float)(r - 1);
  short* lb = &lds[wv][0];

  // Core A-fragments (shared by all 4 points), f16 bits.
  const half8 af0 = __builtin_bit_cast(half8, *(const short8*)(cb + c * 32 + g * 8));
  const half8 af1 = __builtin_bit_cast(half8, *(const short8*)(cb + 512 + c * 32 + g * 8));

  // ---- Lane-parallel position math (lanes 0..11 carry real work) ----
  const int tt = (t < 12) ? t : 11;          // stay in bounds for last wave
  const float q = pts[n0 * 3 + tt];          // lane t -> (point tt/3, axis tt%3)
  const int a = tt - (tt / 3) * 3;           // 0=x, 1=y, 2=z
  float pos = fminf(fmaxf((q + 1.0f) * half_rm1, 0.0f), (float)(r - 1));
  const int i0 = (int)pos;
  const int i1 = min(i0 + 1, r - 1);
  const float w = pos - (float)i0;
  const unsigned base = (unsigned)(a * r) * 256u;          // axis base, bytes
  const int off0 = (int)(base + (unsigned)i0 * 256u);      // row byte offsets
  const int off1 = (int)(base + (unsigned)i1 * 256u);
  const unsigned hb = (unsigned short)hbits(w);
  const int wsp = (int)(hb | (hb << 16));                  // f16 splat {w,w}

  // Staging offsets for MY point (p = g): z from lane 3g+2, y 3g+1, x 3g+0.
  const int lp = g * 3;
  const int zo0 = __shfl(off0, lp + 2), zo1 = __shfl(off1, lp + 2);
  const int yo0 = __shfl(off0, lp + 1), yo1 = __shfl(off1, lp + 1);
  const int xo0 = __shfl(off0, lp + 0), xo1 = __shfl(off1, lp + 0);

  // Weight splats for all 4 points (broadcast shfl from literal lanes).
  const int wz0i = __shfl(wsp,  2), wy0i = __shfl(wsp,  1), wx0i = __shfl(wsp,  0);
  const int wz1i = __shfl(wsp,  5), wy1i = __shfl(wsp,  4), wx1i = __shfl(wsp,  3);
  const int wz2i = __shfl(wsp,  8), wy2i = __shfl(wsp,  7), wx2i = __shfl(wsp,  6);
  const int wz3i = __shfl(wsp, 11), wy3i = __shfl(wsp, 10), wx3i = __shfl(wsp,  9);

  const char* gtc = (const char*)gt;
  const unsigned coff = (unsigned)c * 16u;

  // Issue all 6 gathers back-to-back (no sinking across the fence).
  const u32x4 vz0 = *(const u32x4*)(gtc + zo0 + coff);
  const u32x4 vz1 = *(const u32x4*)(gtc + zo1 + coff);
  const u32x4 vy0 = *(const u32x4*)(gtc + yo0 + coff);
  const u32x4 vy1 = *(const u32x4*)(gtc + yo1 + coff);
  const u32x4 vx0 = *(const u32x4*)(gtc + xo0 + coff);
  const u32x4 vx1 = *(const u32x4*)(gtc + xo1 + coff);
  __builtin_amdgcn_sched_barrier(0);

  // Stage to LDS: lane t's slice at byte t*16 of each 1KB buffer.
  *(u32x4*)(lb +    0 + t * 8) = vz0;
  *(u32x4*)(lb +  512 + t * 8) = vz1;
  *(u32x4*)(lb + 1024 + t * 8) = vy0;
  *(u32x4*)(lb + 1536 + t * 8) = vy1;
  *(u32x4*)(lb + 2048 + t * 8) = vx0;
  *(u32x4*)(lb + 2560 + t * 8) = vx1;

  __syncthreads();   // real barrier: lgkmcnt(0)+vmcnt(0)+s_barrier

  float res0, res1, res2, res3;
  const int gx = g & 1;   // x-quad index: g>=2 lanes duplicate g-2 (acc==0 there)
#pragma unroll
  for (int p = 0; p < 4; ++p) {
    const int wzi = (p == 0) ? wz0i : (p == 1) ? wz1i : (p == 2) ? wz2i : wz3i;
    const int wyi = (p == 0) ? wy0i : (p == 1) ? wy1i : (p == 2) ? wy2i : wy3i;
    const int wxi = (p == 0) ? wx0i : (p == 1) ? wx1i : (p == 2) ? wx2i : wx3i;
    const __half2 wz2 = __builtin_bit_cast(__half2, wzi);
    const __half2 wy2 = __builtin_bit_cast(__half2, wyi);
    const __half2 wx2 = __builtin_bit_cast(__half2, wxi);

    const int ch = p * 16 + c;
    short8 za = *(const short8*)(lb + ch * 8);
    short8 zb = *(const short8*)(lb + 512 + ch * 8);
    int ya = ((const int*)(lb + 1024))[ch * 4 + g];
    int yb = ((const int*)(lb + 1536))[ch * 4 + g];
    short4v xa = ((const short4v*)(lb + 2048))[ch * 2 + gx];
    short4v xb = ((const short4v*)(lb + 2560))[ch * 2 + gx];

    // az lerp: 4x v_pk_sub + 4x v_pk_fma
    const __half2* zah = reinterpret_cast<const __half2*>(&za);
    const __half2* zbh = reinterpret_cast<const __half2*>(&zb);
    __half2 azh0 = __hfma2(wz2, __hsub2(zbh[0], zah[0]), zah[0]);
    __half2 azh1 = __hfma2(wz2, __hsub2(zbh[1], zah[1]), zah[1]);
    __half2 azh2 = __hfma2(wz2, __hsub2(zbh[2], zah[2]), zah[2]);
    __half2 azh3 = __hfma2(wz2, __hsub2(zbh[3], zah[3]), zah[3]);

    // ay lerp (packed pair), then broadcast lo/hi
    const __half2 yah = __builtin_bit_cast(__half2, ya);
    const __half2 ybh = __builtin_bit_cast(__half2, yb);
    const __half2 ayh = __hfma2(wy2, __hsub2(ybh, yah), yah);
    const __half2 aye2 = __low2half2(ayh);    // {ay[2g],  ay[2g]}
    const __half2 ayo2 = __high2half2(ayh);   // {ay[2g+1],ay[2g+1]}

    // B fragments: products stay in f16 (no conversion at all)
    union { __half2 h2[4]; half8 v8; } b0u, b1u;
    b0u.h2[0] = __hmul2(aye2, azh0); b0u.h2[1] = __hmul2(aye2, azh1);
    b0u.h2[2] = __hmul2(aye2, azh2); b0u.h2[3] = __hmul2(aye2, azh3);
    b1u.h2[0] = __hmul2(ayo2, azh0); b1u.h2[1] = __hmul2(ayo2, azh1);
    b1u.h2[2] = __hmul2(ayo2, azh2); b1u.h2[3] = __hmul2(ayo2, azh3);

    // ax lerp in f16, then cvt 4 values to f32 for the epilogue dot
    const __half2* xah = reinterpret_cast<const __half2*>(&xa);
    const __half2* xbh = reinterpret_cast<const __half2*>(&xb);
    __half2 axh0 = __hfma2(wx2, __hsub2(xbh[0], xah[0]), xah[0]);
    __half2 axh1 = __hfma2(wx2, __hsub2(xbh[1], xah[1]), xah[1]);
    float2 ax01 = __half22float2(axh0);
    float2 ax23 = __half22float2(axh1);

    f32x4 acc = {0.0f, 0.0f, 0.0f, 0.0f};
    acc = __builtin_amdgcn_mfma_f32_16x16x32_f16(af0, b0u.v8, acc, 0, 0, 0);
    acc = __builtin_amdgcn_mfma_f32_16x16x32_f16(af1, b1u.v8, acc, 0, 0, 0);

    float partial = acc[0] * ax01.x;
    partial = fmaf(acc[1], ax01.y, partial);
    partial = fmaf(acc[2], ax23.x, partial);
    partial = fmaf(acc[3], ax23.y, partial);
    partial += __shfl_xor(partial, 16);
    partial += __shfl_xor(partial, 32);
    if (p == 0) res0 = partial;
    else if (p == 1) res1 = partial;
    else if (p == 2) res2 = partial;
    else res3 = partial;
  }

  const float myres = (g == 0) ? res0 : (g == 1) ? res1 : (g == 2) ? res2 : res3;
  out[(n0 + g) * 32 + scale * 16 + c] = myres;
}

extern "C" void kernel_launch(void* const* d_in, const int* in_sizes, int n_in,
                              void* d_out, int out_size, void* d_ws, size_t ws_size,
                              hipStream_t stream) {
  const float* pts   = (const float*)d_in[0];
  const float* g0a   = (const float*)d_in[1];
  const float* g1a   = (const float*)d_in[2];
  const float* g2a   = (const float*)d_in[3];
  const float* corea = (const float*)d_in[4];
  const float* g0b   = (const float*)d_in[5];
  const float* g1b   = (const float*)d_in[6];
  const float* g2b   = (const float*)d_in[7];
  const float* coreb = (const float*)d_in[8];
  float* out = (float*)d_out;

  prep_kernel<<<152, 256, 0, stream>>>(g0a, g1a, g2a, corea, g0b, g1b, g2b, coreb);

  dim3 grid(N_PTS / 16, 2);   // 4 waves/block, 4 points/wave, y = scale
  tucker_mfma<<<grid, 256, 0, stream>>>(pts, out);
}